// Round 4
// baseline (1023.036 us; speedup 1.0000x reference)
//
#include <hip/hip_runtime.h>

// B=4, S=2048, D=1024, H=16, DK=64. RoPE (interleaved pairs) + causal MHA.
// R4: single-wave flash attention (64 q-rows/wave, no barriers, manual
// waitcnt; K/V LDS fragments amortized over 4 q-groups) + RoPE fused into
// QKV GEMM epilogue + merged weight casts.

typedef unsigned short u16;
typedef unsigned int u32;
typedef __attribute__((ext_vector_type(8))) short bf16x8;
typedef __attribute__((ext_vector_type(4))) short bf16x4;
typedef __attribute__((ext_vector_type(4))) float f32x4;
typedef __attribute__((ext_vector_type(4))) unsigned short u16x4;

#define S_LEN 2048
#define DMODEL 1024
#define NHEAD 16
#define DKH 64
#define BATCH 4
#define NT 32  // S_LEN/64 key tiles

static __device__ __forceinline__ u16 f2bf(float f) {
  union { float f; u32 u; } v; v.f = f;
  u32 r = v.u + 0x7fffu + ((v.u >> 16) & 1u);  // RNE
  return (u16)(r >> 16);
}
#if __has_builtin(__builtin_amdgcn_cvt_pk_bf16_f32)
typedef __attribute__((ext_vector_type(2))) __bf16 bf2_t;
static __device__ __forceinline__ u32 pack2bf(float a, float b) {
  union { bf2_t h; u32 u; } cv;
  cv.h = __builtin_amdgcn_cvt_pk_bf16_f32(a, b);
  return cv.u;
}
#else
static __device__ __forceinline__ u32 pack2bf(float a, float b) {
  return (u32)f2bf(a) | ((u32)f2bf(b) << 16);
}
#endif
static __device__ __forceinline__ float fexp2(float x) {
#if __has_builtin(__builtin_amdgcn_exp2f)
  return __builtin_amdgcn_exp2f(x);
#else
  return exp2f(x);
#endif
}
static __device__ __forceinline__ f32x4 mfma16(bf16x8 a, bf16x8 b, f32x4 c) {
  return __builtin_amdgcn_mfma_f32_16x16x32_bf16(a, b, c, 0, 0, 0);
}
#if __has_builtin(__builtin_amdgcn_mfma_f32_16x16x16bf16_1k)
static __device__ __forceinline__ f32x4 mfma16k16(bf16x4 a, bf16x4 b, f32x4 c) {
  return __builtin_amdgcn_mfma_f32_16x16x16bf16_1k(a, b, c, 0, 0, 0);
}
#else
// Emulate K=16 via K=32 with upper half zeroed. A and B use the same
// physical (quad,j) k-slot mapping, so pairing stays consistent -> exact.
static __device__ __forceinline__ f32x4 mfma16k16(bf16x4 a, bf16x4 b, f32x4 c) {
  bf16x8 a8 = {a[0], a[1], a[2], a[3], 0, 0, 0, 0};
  bf16x8 b8 = {b[0], b[1], b[2], b[3], 0, 0, 0, 0};
  return mfma16(a8, b8, c);
}
#endif
// Async global->LDS, 16B per lane. LDS dest = wave-uniform base + lane*16.
static __device__ __forceinline__ void glds16(const void* g, void* l) {
  __builtin_amdgcn_global_load_lds((const __attribute__((address_space(1))) u32*)g,
                                   (__attribute__((address_space(3))) u32*)l, 16, 0, 0);
}

__global__ __launch_bounds__(256) void cast_bf16(const float* __restrict__ src,
                                                 u16* __restrict__ dst, int n4) {
  int i = blockIdx.x * 256 + threadIdx.x;
  if (i >= n4) return;
  const float* s = src + (size_t)i * 4;
  u16x4 o;
  o.x = f2bf(s[0]); o.y = f2bf(s[1]); o.z = f2bf(s[2]); o.w = f2bf(s[3]);
  ((u16x4*)dst)[i] = o;
}

// All four weight matrices -> one contiguous bf16 block [4096][1024].
__global__ __launch_bounds__(256) void cast_w4(const float* __restrict__ a,
                                               const float* __restrict__ b,
                                               const float* __restrict__ c2,
                                               const float* __restrict__ d,
                                               u16* __restrict__ dst) {
  const int per = DMODEL * DMODEL / 4;  // 262144 quads per matrix
  int i = blockIdx.x * 256 + threadIdx.x;
  if (i >= 4 * per) return;
  const float* srcs[4] = {a, b, c2, d};
  const float* s = srcs[i >> 18] + (size_t)(i & (per - 1)) * 4;
  u16x4 o;
  o.x = f2bf(s[0]); o.y = f2bf(s[1]); o.z = f2bf(s[2]); o.w = f2bf(s[3]);
  ((u16x4*)dst)[i] = o;
}

// C[m,n] = sum_k A[m,k] * W[n,k]. 128x128 tile, BK=64, glds staging.
// mode 0: QKV epilogue with fused RoPE (+q pre-scale by 0.125*log2e):
//         n<1024 -> oq (roped), <2048 -> ok (roped), else ov as [B,H,DK,S].
// mode 2: fp32 store to of.
__global__ __launch_bounds__(256) void gemm128(const u16* __restrict__ A,
                                               const u16* __restrict__ W,
                                               u16* __restrict__ oq,
                                               u16* __restrict__ ok,
                                               u16* __restrict__ ov,
                                               float* __restrict__ of,
                                               const int* __restrict__ pos,
                                               int mode) {
  __shared__ __attribute__((aligned(16))) u16 As[128 * 64];
  __shared__ __attribute__((aligned(16))) u16 Bs[128 * 64];
  const int m0 = blockIdx.x * 128, n0 = blockIdx.y * 128;
  const int tid = threadIdx.x, lane = tid & 63, wave = tid >> 6;
  const int quad = lane >> 4, c = lane & 15;
  const int wm = (wave & 1) * 64, wn = (wave >> 1) * 64;
  const int ls = lane >> 3, lc = lane & 7;
  f32x4 acc[4][4] = {};
  for (int ko = 0; ko < DMODEL; ko += 64) {
#pragma unroll
    for (int i = 0; i < 4; ++i) {
      int rb = i * 32 + wave * 8;
      int r = rb + ls;
      int kA = ko + 8 * (lc ^ (r & 7));
      glds16(&A[(size_t)(m0 + r) * DMODEL + kA], &As[rb * 64]);
      glds16(&W[(size_t)(n0 + r) * DMODEL + kA], &Bs[rb * 64]);
    }
    __syncthreads();
#pragma unroll
    for (int t = 0; t < 2; ++t) {
      bf16x8 af[4], bfr[4];
#pragma unroll
      for (int mb = 0; mb < 4; ++mb) {
        int r = wm + mb * 16 + c;
        af[mb] = *(const bf16x8*)&As[r * 64 + 8 * ((t * 4 + quad) ^ (r & 7))];
      }
#pragma unroll
      for (int nb = 0; nb < 4; ++nb) {
        int r = wn + nb * 16 + c;
        bfr[nb] = *(const bf16x8*)&Bs[r * 64 + 8 * ((t * 4 + quad) ^ (r & 7))];
      }
#pragma unroll
      for (int mb = 0; mb < 4; ++mb)
#pragma unroll
        for (int nb = 0; nb < 4; ++nb)
          acc[mb][nb] = mfma16(af[mb], bfr[nb], acc[mb][nb]);
    }
    __syncthreads();
  }
  const float QSCALE = 0.18033688011112042f;   // 0.125 * log2(e)
  const float PW = 0.4152410118609203f;        // log2(10000)/32
#pragma unroll
  for (int mb = 0; mb < 4; ++mb) {
    int mrow = m0 + wm + mb * 16 + quad * 4;
    float fpos[4];
    if (mode == 0 && n0 + wn < 2 * DMODEL) {
#pragma unroll
      for (int r = 0; r < 4; ++r) fpos[r] = (float)pos[(mrow + r) & (S_LEN - 1)];
    }
#pragma unroll
    for (int nb = 0; nb < 4; ++nb) {
      int n = n0 + wn + nb * 16 + c;
      f32x4 v = acc[mb][nb];
      if (mode == 2) {
#pragma unroll
        for (int r = 0; r < 4; ++r) of[(size_t)(mrow + r) * DMODEL + n] = v[r];
      } else if (n < 2 * DMODEL) {
        // fused RoPE on fp32 accumulators
        int nn = n & (DMODEL - 1);
        int p = (nn & 63) >> 1;
        float invf = fexp2(-(float)p * PW);
        bool even = !(n & 1);
        bool isq = n < DMODEL;
        u16* dst = isq ? oq : ok;
#pragma unroll
        for (int r = 0; r < 4; ++r) {
          float other = __shfl_xor(v[r], 1);
          float x1 = even ? v[r] : other;
          float x2 = even ? other : v[r];
          float ph = fpos[r] * invf;
          float sn, cs;
          sincosf(ph, &sn, &cs);
          float res = even ? (x1 * cs - x2 * sn) : (x1 * sn + x2 * cs);
          if (isq) res *= QSCALE;
          dst[(size_t)(mrow + r) * DMODEL + nn] = f2bf(res);
        }
      } else {
        int nn = n - 2 * DMODEL;
        int h = nn >> 6, d = nn & 63;
        int b = mrow >> 11, s = mrow & (S_LEN - 1);
        u16x4 p4;
        p4.x = f2bf(v[0]); p4.y = f2bf(v[1]); p4.z = f2bf(v[2]); p4.w = f2bf(v[3]);
        *(u16x4*)&ov[((size_t)(b * NHEAD + h) * DKH + d) * S_LEN + s] = p4;
      }
    }
  }
}

// Flash attention, S^T formulation, no-max softmax (scores |s|<<1, softmax
// shift-invariant; q pre-scaled so scores exit QK^T in log2 domain).
// ONE WAVE per block, 64 q-rows per wave (4 x 16-col MFMA groups); K/V LDS
// fragments are group-invariant -> read once, use 4x. No __syncthreads:
// ordering via explicit s_waitcnt (vmcnt for glds arrival, lgkmcnt before
// re-staging). Grid (NT, B*H) = 2048 single-wave blocks -> dynamic backfill
// over the causal imbalance.
__global__ __launch_bounds__(64) void attn4(const u16* __restrict__ qb,
                                            const u16* __restrict__ kb,
                                            const u16* __restrict__ vt,
                                            u16* __restrict__ ab) {
  __shared__ __attribute__((aligned(16))) u16 Ks[64 * 64];  // [key][d] swizzled
  __shared__ __attribute__((aligned(16))) u16 Vs[64 * 64];  // [d][key] swizzled
  const int qt = blockIdx.x;
  const int bh = blockIdx.y, b = bh >> 4, h = bh & 15;
  const int lane = threadIdx.x & 63;
  const int quad = lane >> 4, c = lane & 15;
  const int ls = lane >> 3, lc = lane & 7;
  const int q0 = qt * 64;
  const float NEG = -3.0e38f;

  bf16x8 qf[4][2];
#pragma unroll
  for (int g = 0; g < 4; ++g) {
    const u16* qp = qb + (size_t)(b * S_LEN + q0 + g * 16 + c) * DMODEL + h * DKH;
    qf[g][0] = *(const bf16x8*)&qp[quad * 8];
    qf[g][1] = *(const bf16x8*)&qp[32 + quad * 8];
  }
  float li[4] = {0.f, 0.f, 0.f, 0.f};
  f32x4 od[4][4] = {};  // [q-group][d-block]

#pragma unroll 1
  for (int j = 0; j <= qt; ++j) {
    // all ds_reads of the previous iteration must have completed
    asm volatile("s_waitcnt lgkmcnt(0)" ::: "memory");
#pragma unroll
    for (int i = 0; i < 8; ++i) {
      int r = i * 8 + ls;
      int col = 8 * (lc ^ (r & 7));
      glds16(&kb[(size_t)(b * S_LEN + j * 64 + r) * DMODEL + h * DKH + col], &Ks[i * 512]);
      glds16(&vt[((size_t)bh * DKH + r) * S_LEN + j * 64 + col], &Vs[i * 512]);
    }
    asm volatile("s_waitcnt vmcnt(0)" ::: "memory");

    // K fragments (shared across all 4 q-groups)
    bf16x8 kf[4][2];
#pragma unroll
    for (int kbi = 0; kbi < 4; ++kbi) {
      int r = kbi * 16 + c;
      kf[kbi][0] = *(const bf16x8*)&Ks[r * 64 + 8 * (quad ^ (r & 7))];
      kf[kbi][1] = *(const bf16x8*)&Ks[r * 64 + 8 * ((4 + quad) ^ (r & 7))];
    }
    // V fragments K=16 (shared across all 4 q-groups)
    bf16x4 vf[4][4];  // [d-block][key-block]
#pragma unroll
    for (int db = 0; db < 4; ++db) {
      int r = db * 16 + c;
#pragma unroll
      for (int kbi = 0; kbi < 4; ++kbi) {
        int g2 = kbi * 2 + (quad >> 1);
        vf[db][kbi] = *(const bf16x4*)&Vs[r * 64 + 8 * (g2 ^ (r & 7)) + (quad & 1) * 4];
      }
    }
    const bool diag = (j == qt);
#pragma unroll
    for (int g = 0; g < 4; ++g) {
      f32x4 sc[4];
#pragma unroll
      for (int kbi = 0; kbi < 4; ++kbi) {
        f32x4 a = {};
        a = mfma16(kf[kbi][0], qf[g][0], a);
        a = mfma16(kf[kbi][1], qf[g][1], a);
        sc[kbi] = a;  // log2-domain scores (q pre-scaled)
      }
      if (diag) {
#pragma unroll
        for (int kbi = 0; kbi < 4; ++kbi)
#pragma unroll
          for (int r = 0; r < 4; ++r)
            if (kbi * 16 + quad * 4 + r > g * 16 + c) sc[kbi][r] = NEG;
      }
      float rs = 0.f;
#pragma unroll
      for (int kbi = 0; kbi < 4; ++kbi)
#pragma unroll
        for (int r = 0; r < 4; ++r) {
          float pv = fexp2(sc[kbi][r]);
          sc[kbi][r] = pv;
          rs += pv;
        }
      rs += __shfl_xor(rs, 16);
      rs += __shfl_xor(rs, 32);
      li[g] += rs;
      bf16x4 pkv[4];
#pragma unroll
      for (int kbi = 0; kbi < 4; ++kbi) {
        union { u32 w[2]; bf16x4 v; } pk;
        pk.w[0] = pack2bf(sc[kbi][0], sc[kbi][1]);
        pk.w[1] = pack2bf(sc[kbi][2], sc[kbi][3]);
        pkv[kbi] = pk.v;
      }
#pragma unroll
      for (int db = 0; db < 4; ++db)
#pragma unroll
        for (int kbi = 0; kbi < 4; ++kbi)
          od[g][db] = mfma16k16(vf[db][kbi], pkv[kbi], od[g][db]);
    }
  }

#pragma unroll
  for (int g = 0; g < 4; ++g) {
    float inv = 1.0f / li[g];
    u16* op = ab + (size_t)(b * S_LEN + q0 + g * 16 + c) * DMODEL + h * DKH;
#pragma unroll
    for (int db = 0; db < 4; ++db) {
      u16x4 o4;
      o4.x = f2bf(od[g][db][0] * inv);
      o4.y = f2bf(od[g][db][1] * inv);
      o4.z = f2bf(od[g][db][2] * inv);
      o4.w = f2bf(od[g][db][3] * inv);
      *(u16x4*)&op[db * 16 + quad * 4] = o4;
    }
  }
}

extern "C" void kernel_launch(void* const* d_in, const int* in_sizes, int n_in,
                              void* d_out, int out_size, void* d_ws, size_t ws_size,
                              hipStream_t stream) {
  const float* x = (const float*)d_in[0];
  const int* pos = (const int*)d_in[1];
  const float* Wq = (const float*)d_in[2];
  const float* Wk = (const float*)d_in[3];
  const float* Wv = (const float*)d_in[4];
  const float* Wo = (const float*)d_in[5];
  float* out = (float*)d_out;

  char* w = (char*)d_ws;
  size_t o = 0;
  auto take = [&](size_t nbytes) {
    char* p = w + o;
    o += (nbytes + 255) & ~(size_t)255;
    return p;
  };
  const size_t actBytes = (size_t)BATCH * S_LEN * DMODEL * 2;
  const size_t wElems = (size_t)DMODEL * DMODEL;
  u16* xb   = (u16*)take(actBytes);
  u16* Wall = (u16*)take(4 * wElems * 2);  // Wq;Wk;Wv;Wo bf16
  u16* qb   = (u16*)take(actBytes);
  u16* kb   = (u16*)take(actBytes);
  u16* vt   = (u16*)take(actBytes);  // [B,H,DK,S]
  u16* ab   = (u16*)take(actBytes);

  int n4x = BATCH * S_LEN * DMODEL / 4;
  cast_bf16<<<(n4x + 255) / 256, 256, 0, stream>>>(x, xb, n4x);
  int n4w = 4 * DMODEL * DMODEL / 4;
  cast_w4<<<(n4w + 255) / 256, 256, 0, stream>>>(Wq, Wk, Wv, Wo, Wall);

  // Fused QKV (+RoPE epilogue): [8192,1024] x [3072,1024]^T
  gemm128<<<dim3(BATCH * S_LEN / 128, 3 * DMODEL / 128), 256, 0, stream>>>(
      xb, Wall, qb, kb, vt, nullptr, pos, 0);

  attn4<<<dim3(NT, BATCH * NHEAD), 64, 0, stream>>>(qb, kb, vt, ab);

  gemm128<<<dim3(BATCH * S_LEN / 128, DMODEL / 128), 256, 0, stream>>>(
      ab, Wall + 3 * wElems, nullptr, nullptr, nullptr, out, nullptr, 2);
}

// Round 5
// 359.829 us; speedup vs baseline: 2.8431x; 2.8431x over previous
//
#include <hip/hip_runtime.h>

// B=4, S=2048, D=1024, H=16, DK=64. RoPE (interleaved pairs) + causal MHA.
// R5: revert RoPE fusion (R4's sincosf-in-epilogue caused acc spill -> 2.2GB
// scratch traffic). R3 GEMM + standalone rope + R4 single-wave attention
// (64 q-rows/wave, no barriers, K/V LDS fragments amortized 4x).

typedef unsigned short u16;
typedef unsigned int u32;
typedef __attribute__((ext_vector_type(8))) short bf16x8;
typedef __attribute__((ext_vector_type(4))) short bf16x4;
typedef __attribute__((ext_vector_type(4))) float f32x4;
typedef __attribute__((ext_vector_type(4))) unsigned short u16x4;

#define S_LEN 2048
#define DMODEL 1024
#define NHEAD 16
#define DKH 64
#define BATCH 4
#define NT 32  // S_LEN/64 key tiles

static __device__ __forceinline__ u16 f2bf(float f) {
  union { float f; u32 u; } v; v.f = f;
  u32 r = v.u + 0x7fffu + ((v.u >> 16) & 1u);  // RNE
  return (u16)(r >> 16);
}
#if __has_builtin(__builtin_amdgcn_cvt_pk_bf16_f32)
typedef __attribute__((ext_vector_type(2))) __bf16 bf2_t;
static __device__ __forceinline__ u32 pack2bf(float a, float b) {
  union { bf2_t h; u32 u; } cv;
  cv.h = __builtin_amdgcn_cvt_pk_bf16_f32(a, b);
  return cv.u;
}
#else
static __device__ __forceinline__ u32 pack2bf(float a, float b) {
  return (u32)f2bf(a) | ((u32)f2bf(b) << 16);
}
#endif
static __device__ __forceinline__ float fexp2(float x) {
#if __has_builtin(__builtin_amdgcn_exp2f)
  return __builtin_amdgcn_exp2f(x);
#else
  return exp2f(x);
#endif
}
static __device__ __forceinline__ f32x4 mfma16(bf16x8 a, bf16x8 b, f32x4 c) {
  return __builtin_amdgcn_mfma_f32_16x16x32_bf16(a, b, c, 0, 0, 0);
}
#if __has_builtin(__builtin_amdgcn_mfma_f32_16x16x16bf16_1k)
static __device__ __forceinline__ f32x4 mfma16k16(bf16x4 a, bf16x4 b, f32x4 c) {
  return __builtin_amdgcn_mfma_f32_16x16x16bf16_1k(a, b, c, 0, 0, 0);
}
#else
// Emulate K=16 via K=32 with upper half zeroed (same (quad,j) k-slot map -> exact).
static __device__ __forceinline__ f32x4 mfma16k16(bf16x4 a, bf16x4 b, f32x4 c) {
  bf16x8 a8 = {a[0], a[1], a[2], a[3], 0, 0, 0, 0};
  bf16x8 b8 = {b[0], b[1], b[2], b[3], 0, 0, 0, 0};
  return mfma16(a8, b8, c);
}
#endif
// Async global->LDS, 16B per lane. LDS dest = wave-uniform base + lane*16.
static __device__ __forceinline__ void glds16(const void* g, void* l) {
  __builtin_amdgcn_global_load_lds((const __attribute__((address_space(1))) u32*)g,
                                   (__attribute__((address_space(3))) u32*)l, 16, 0, 0);
}

__global__ __launch_bounds__(256) void cast_bf16(const float* __restrict__ src,
                                                 u16* __restrict__ dst, int n4) {
  int i = blockIdx.x * 256 + threadIdx.x;
  if (i >= n4) return;
  const float* s = src + (size_t)i * 4;
  u16x4 o;
  o.x = f2bf(s[0]); o.y = f2bf(s[1]); o.z = f2bf(s[2]); o.w = f2bf(s[3]);
  ((u16x4*)dst)[i] = o;
}

// All four weight matrices -> one contiguous bf16 block [4096][1024].
__global__ __launch_bounds__(256) void cast_w4(const float* __restrict__ a,
                                               const float* __restrict__ b,
                                               const float* __restrict__ c2,
                                               const float* __restrict__ d,
                                               u16* __restrict__ dst) {
  const int per = DMODEL * DMODEL / 4;  // 2^18 quads per matrix
  int i = blockIdx.x * 256 + threadIdx.x;
  if (i >= 4 * per) return;
  int sel = i >> 18;
  const float* s = (sel == 0) ? a : (sel == 1) ? b : (sel == 2) ? c2 : d;
  s += (size_t)(i & (per - 1)) * 4;
  u16x4 o;
  o.x = f2bf(s[0]); o.y = f2bf(s[1]); o.z = f2bf(s[2]); o.w = f2bf(s[3]);
  ((u16x4*)dst)[i] = o;
}

// C[m,n] = sum_k A[m,k] * W[n,k]. 128x128 tile, BK=64, glds staging.
// mode 0: QKV epilogue (n<1024 -> oq, <2048 -> ok, else ov as [B,H,DK,S]).
// mode 2: fp32 store to of.
__global__ __launch_bounds__(256) void gemm128(const u16* __restrict__ A,
                                               const u16* __restrict__ W,
                                               u16* __restrict__ oq,
                                               u16* __restrict__ ok,
                                               u16* __restrict__ ov,
                                               float* __restrict__ of,
                                               int mode) {
  __shared__ __attribute__((aligned(16))) u16 As[128 * 64];
  __shared__ __attribute__((aligned(16))) u16 Bs[128 * 64];
  const int m0 = blockIdx.x * 128, n0 = blockIdx.y * 128;
  const int tid = threadIdx.x, lane = tid & 63, wave = tid >> 6;
  const int quad = lane >> 4, c = lane & 15;
  const int wm = (wave & 1) * 64, wn = (wave >> 1) * 64;
  const int ls = lane >> 3, lc = lane & 7;
  f32x4 acc[4][4] = {};
  for (int ko = 0; ko < DMODEL; ko += 64) {
#pragma unroll
    for (int i = 0; i < 4; ++i) {
      int rb = i * 32 + wave * 8;
      int r = rb + ls;
      int kA = ko + 8 * (lc ^ (r & 7));
      glds16(&A[(size_t)(m0 + r) * DMODEL + kA], &As[rb * 64]);
      glds16(&W[(size_t)(n0 + r) * DMODEL + kA], &Bs[rb * 64]);
    }
    __syncthreads();
#pragma unroll
    for (int t = 0; t < 2; ++t) {
      bf16x8 af[4], bfr[4];
#pragma unroll
      for (int mb = 0; mb < 4; ++mb) {
        int r = wm + mb * 16 + c;
        af[mb] = *(const bf16x8*)&As[r * 64 + 8 * ((t * 4 + quad) ^ (r & 7))];
      }
#pragma unroll
      for (int nb = 0; nb < 4; ++nb) {
        int r = wn + nb * 16 + c;
        bfr[nb] = *(const bf16x8*)&Bs[r * 64 + 8 * ((t * 4 + quad) ^ (r & 7))];
      }
#pragma unroll
      for (int mb = 0; mb < 4; ++mb)
#pragma unroll
        for (int nb = 0; nb < 4; ++nb)
          acc[mb][nb] = mfma16(af[mb], bfr[nb], acc[mb][nb]);
    }
    __syncthreads();
  }
#pragma unroll
  for (int mb = 0; mb < 4; ++mb) {
    int mrow = m0 + wm + mb * 16 + quad * 4;
#pragma unroll
    for (int nb = 0; nb < 4; ++nb) {
      int n = n0 + wn + nb * 16 + c;
      f32x4 v = acc[mb][nb];
      if (mode == 2) {
#pragma unroll
        for (int r = 0; r < 4; ++r) of[(size_t)(mrow + r) * DMODEL + n] = v[r];
      } else if (n < DMODEL) {
#pragma unroll
        for (int r = 0; r < 4; ++r) oq[(size_t)(mrow + r) * DMODEL + n] = f2bf(v[r]);
      } else if (n < 2 * DMODEL) {
#pragma unroll
        for (int r = 0; r < 4; ++r) ok[(size_t)(mrow + r) * DMODEL + (n - DMODEL)] = f2bf(v[r]);
      } else {
        int nn = n - 2 * DMODEL;
        int h = nn >> 6, d = nn & 63;
        int b = mrow >> 11, s = mrow & (S_LEN - 1);
        u16x4 p4;
        p4.x = f2bf(v[0]); p4.y = f2bf(v[1]); p4.z = f2bf(v[2]); p4.w = f2bf(v[3]);
        *(u16x4*)&ov[((size_t)(b * NHEAD + h) * DKH + d) * S_LEN + s] = p4;
      }
    }
  }
}

// In-place RoPE on q and k; q additionally pre-scaled by 0.125*log2(e) so
// attention scores exit QK^T MFMA directly in the log2 domain.
__global__ __launch_bounds__(256) void rope_qk(u16* __restrict__ q, u16* __restrict__ k,
                                               const int* __restrict__ pos) {
  const float QSCALE = 0.18033688011112042f;  // 0.125 * log2(e)
  int i = blockIdx.x * 256 + threadIdx.x;  // pair index over [8192][512]
  if (i >= BATCH * S_LEN * DMODEL / 2) return;
  int m = i >> 9;
  int pr = i & 511;
  int p = pr & 31;
  int s = m & (S_LEN - 1);
  float ph = (float)pos[s] * powf(10000.0f, -(float)(2 * p) / 64.0f);
  float sn, cs;
  sincosf(ph, &sn, &cs);
  unsigned vq = ((unsigned*)q)[i];
  float x1, x2, r1, r2;
  { union { u32 u; float f; } a, b2; a.u = vq << 16; b2.u = vq & 0xffff0000u;
    x1 = a.f; x2 = b2.f; }
  r1 = (x1 * cs - x2 * sn) * QSCALE; r2 = (x1 * sn + x2 * cs) * QSCALE;
  ((unsigned*)q)[i] = pack2bf(r1, r2);
  unsigned vk = ((unsigned*)k)[i];
  { union { u32 u; float f; } a, b2; a.u = vk << 16; b2.u = vk & 0xffff0000u;
    x1 = a.f; x2 = b2.f; }
  r1 = x1 * cs - x2 * sn; r2 = x1 * sn + x2 * cs;
  ((unsigned*)k)[i] = pack2bf(r1, r2);
}

// Flash attention, S^T formulation, no-max softmax (scores |s|<<1, softmax
// shift-invariant; q pre-scaled so scores exit QK^T in log2 domain).
// ONE WAVE per block, 64 q-rows per wave (4 x 16-col MFMA groups); K/V LDS
// fragments are group-invariant -> read once, use 4x. No __syncthreads:
// ordering via explicit s_waitcnt (vmcnt for glds arrival, lgkmcnt before
// re-staging). Grid (NT, B*H) = 2048 single-wave blocks -> dynamic backfill
// over the causal imbalance.
__global__ __launch_bounds__(64) void attn4(const u16* __restrict__ qb,
                                            const u16* __restrict__ kb,
                                            const u16* __restrict__ vt,
                                            u16* __restrict__ ab) {
  __shared__ __attribute__((aligned(16))) u16 Ks[64 * 64];  // [key][d] swizzled
  __shared__ __attribute__((aligned(16))) u16 Vs[64 * 64];  // [d][key] swizzled
  const int qt = blockIdx.x;
  const int bh = blockIdx.y, b = bh >> 4, h = bh & 15;
  const int lane = threadIdx.x & 63;
  const int quad = lane >> 4, c = lane & 15;
  const int ls = lane >> 3, lc = lane & 7;
  const int q0 = qt * 64;
  const float NEG = -3.0e38f;

  bf16x8 qf[4][2];
#pragma unroll
  for (int g = 0; g < 4; ++g) {
    const u16* qp = qb + (size_t)(b * S_LEN + q0 + g * 16 + c) * DMODEL + h * DKH;
    qf[g][0] = *(const bf16x8*)&qp[quad * 8];
    qf[g][1] = *(const bf16x8*)&qp[32 + quad * 8];
  }
  float li[4] = {0.f, 0.f, 0.f, 0.f};
  f32x4 od[4][4] = {};  // [q-group][d-block]

#pragma unroll 1
  for (int j = 0; j <= qt; ++j) {
    // all ds_reads of the previous iteration must have completed
    asm volatile("s_waitcnt lgkmcnt(0)" ::: "memory");
#pragma unroll
    for (int i = 0; i < 8; ++i) {
      int r = i * 8 + ls;
      int col = 8 * (lc ^ (r & 7));
      glds16(&kb[(size_t)(b * S_LEN + j * 64 + r) * DMODEL + h * DKH + col], &Ks[i * 512]);
      glds16(&vt[((size_t)bh * DKH + r) * S_LEN + j * 64 + col], &Vs[i * 512]);
    }
    asm volatile("s_waitcnt vmcnt(0)" ::: "memory");

    // K fragments (shared across all 4 q-groups)
    bf16x8 kf[4][2];
#pragma unroll
    for (int kbi = 0; kbi < 4; ++kbi) {
      int r = kbi * 16 + c;
      kf[kbi][0] = *(const bf16x8*)&Ks[r * 64 + 8 * (quad ^ (r & 7))];
      kf[kbi][1] = *(const bf16x8*)&Ks[r * 64 + 8 * ((4 + quad) ^ (r & 7))];
    }
    // V fragments K=16 (shared across all 4 q-groups)
    bf16x4 vf[4][4];  // [d-block][key-block]
#pragma unroll
    for (int db = 0; db < 4; ++db) {
      int r = db * 16 + c;
#pragma unroll
      for (int kbi = 0; kbi < 4; ++kbi) {
        int g2 = kbi * 2 + (quad >> 1);
        vf[db][kbi] = *(const bf16x4*)&Vs[r * 64 + 8 * (g2 ^ (r & 7)) + (quad & 1) * 4];
      }
    }
    const bool diag = (j == qt);
#pragma unroll
    for (int g = 0; g < 4; ++g) {
      f32x4 sc[4];
#pragma unroll
      for (int kbi = 0; kbi < 4; ++kbi) {
        f32x4 a = {};
        a = mfma16(kf[kbi][0], qf[g][0], a);
        a = mfma16(kf[kbi][1], qf[g][1], a);
        sc[kbi] = a;  // log2-domain scores (q pre-scaled)
      }
      if (diag) {
#pragma unroll
        for (int kbi = 0; kbi < 4; ++kbi)
#pragma unroll
          for (int r = 0; r < 4; ++r)
            if (kbi * 16 + quad * 4 + r > g * 16 + c) sc[kbi][r] = NEG;
      }
      float rs = 0.f;
#pragma unroll
      for (int kbi = 0; kbi < 4; ++kbi)
#pragma unroll
        for (int r = 0; r < 4; ++r) {
          float pv = fexp2(sc[kbi][r]);
          sc[kbi][r] = pv;
          rs += pv;
        }
      rs += __shfl_xor(rs, 16);
      rs += __shfl_xor(rs, 32);
      li[g] += rs;
      bf16x4 pkv[4];
#pragma unroll
      for (int kbi = 0; kbi < 4; ++kbi) {
        union { u32 w[2]; bf16x4 v; } pk;
        pk.w[0] = pack2bf(sc[kbi][0], sc[kbi][1]);
        pk.w[1] = pack2bf(sc[kbi][2], sc[kbi][3]);
        pkv[kbi] = pk.v;
      }
#pragma unroll
      for (int db = 0; db < 4; ++db)
#pragma unroll
        for (int kbi = 0; kbi < 4; ++kbi)
          od[g][db] = mfma16k16(vf[db][kbi], pkv[kbi], od[g][db]);
    }
  }

#pragma unroll
  for (int g = 0; g < 4; ++g) {
    float inv = 1.0f / li[g];
    u16* op = ab + (size_t)(b * S_LEN + q0 + g * 16 + c) * DMODEL + h * DKH;
#pragma unroll
    for (int db = 0; db < 4; ++db) {
      u16x4 o4;
      o4.x = f2bf(od[g][db][0] * inv);
      o4.y = f2bf(od[g][db][1] * inv);
      o4.z = f2bf(od[g][db][2] * inv);
      o4.w = f2bf(od[g][db][3] * inv);
      *(u16x4*)&op[db * 16 + quad * 4] = o4;
    }
  }
}

extern "C" void kernel_launch(void* const* d_in, const int* in_sizes, int n_in,
                              void* d_out, int out_size, void* d_ws, size_t ws_size,
                              hipStream_t stream) {
  const float* x = (const float*)d_in[0];
  const int* pos = (const int*)d_in[1];
  const float* Wq = (const float*)d_in[2];
  const float* Wk = (const float*)d_in[3];
  const float* Wv = (const float*)d_in[4];
  const float* Wo = (const float*)d_in[5];
  float* out = (float*)d_out;

  char* w = (char*)d_ws;
  size_t o = 0;
  auto take = [&](size_t nbytes) {
    char* p = w + o;
    o += (nbytes + 255) & ~(size_t)255;
    return p;
  };
  const size_t actBytes = (size_t)BATCH * S_LEN * DMODEL * 2;
  const size_t wElems = (size_t)DMODEL * DMODEL;
  u16* xb   = (u16*)take(actBytes);
  u16* Wall = (u16*)take(4 * wElems * 2);  // Wq;Wk;Wv;Wo bf16
  u16* qb   = (u16*)take(actBytes);
  u16* kb   = (u16*)take(actBytes);
  u16* vt   = (u16*)take(actBytes);  // [B,H,DK,S]
  u16* ab   = (u16*)take(actBytes);

  int n4x = BATCH * S_LEN * DMODEL / 4;
  cast_bf16<<<(n4x + 255) / 256, 256, 0, stream>>>(x, xb, n4x);
  int n4w = 4 * DMODEL * DMODEL / 4;
  cast_w4<<<(n4w + 255) / 256, 256, 0, stream>>>(Wq, Wk, Wv, Wo, Wall);

  // Fused QKV: [8192,1024] x [3072,1024]^T
  gemm128<<<dim3(BATCH * S_LEN / 128, 3 * DMODEL / 128), 256, 0, stream>>>(
      xb, Wall, qb, kb, vt, nullptr, 0);

  int npair = BATCH * S_LEN * DMODEL / 2;
  rope_qk<<<(npair + 255) / 256, 256, 0, stream>>>(qb, kb, pos);

  attn4<<<dim3(NT, BATCH * NHEAD), 64, 0, stream>>>(qb, kb, vt, ab);

  gemm128<<<dim3(BATCH * S_LEN / 128, DMODEL / 128), 256, 0, stream>>>(
      ab, Wall + 3 * wElems, nullptr, nullptr, nullptr, out, 2);
}

// Round 6
// 354.732 us; speedup vs baseline: 2.8840x; 1.0144x over previous
//
#include <hip/hip_runtime.h>

// B=4, S=2048, D=1024, H=16, DK=64. RoPE (interleaved pairs) + causal MHA.
// R6: LDS-free flash attention. 4-wave blocks (>=4 waves/workgroup: gfx950
// residency is capped at ~2-3 workgroups/CU — single-wave blocks gave 2
// waves/CU in R5). Each wave owns 64 q-rows of one (bh, qt); K/V fragments
// loaded straight from global in MFMA layout. Balanced qt sets per block.

typedef unsigned short u16;
typedef unsigned int u32;
typedef __attribute__((ext_vector_type(8))) short bf16x8;
typedef __attribute__((ext_vector_type(4))) short bf16x4;
typedef __attribute__((ext_vector_type(4))) float f32x4;
typedef __attribute__((ext_vector_type(4))) unsigned short u16x4;

#define S_LEN 2048
#define DMODEL 1024
#define NHEAD 16
#define DKH 64
#define BATCH 4
#define NT 32  // S_LEN/64 key tiles

static __device__ __forceinline__ u16 f2bf(float f) {
  union { float f; u32 u; } v; v.f = f;
  u32 r = v.u + 0x7fffu + ((v.u >> 16) & 1u);  // RNE
  return (u16)(r >> 16);
}
#if __has_builtin(__builtin_amdgcn_cvt_pk_bf16_f32)
typedef __attribute__((ext_vector_type(2))) __bf16 bf2_t;
static __device__ __forceinline__ u32 pack2bf(float a, float b) {
  union { bf2_t h; u32 u; } cv;
  cv.h = __builtin_amdgcn_cvt_pk_bf16_f32(a, b);
  return cv.u;
}
#else
static __device__ __forceinline__ u32 pack2bf(float a, float b) {
  return (u32)f2bf(a) | ((u32)f2bf(b) << 16);
}
#endif
static __device__ __forceinline__ float fexp2(float x) {
#if __has_builtin(__builtin_amdgcn_exp2f)
  return __builtin_amdgcn_exp2f(x);
#else
  return exp2f(x);
#endif
}
static __device__ __forceinline__ f32x4 mfma16(bf16x8 a, bf16x8 b, f32x4 c) {
  return __builtin_amdgcn_mfma_f32_16x16x32_bf16(a, b, c, 0, 0, 0);
}
#if __has_builtin(__builtin_amdgcn_mfma_f32_16x16x16bf16_1k)
static __device__ __forceinline__ f32x4 mfma16k16(bf16x4 a, bf16x4 b, f32x4 c) {
  return __builtin_amdgcn_mfma_f32_16x16x16bf16_1k(a, b, c, 0, 0, 0);
}
#else
// Emulate K=16 via K=32 with upper half zeroed (same (quad,j) k-slot map -> exact).
static __device__ __forceinline__ f32x4 mfma16k16(bf16x4 a, bf16x4 b, f32x4 c) {
  bf16x8 a8 = {a[0], a[1], a[2], a[3], 0, 0, 0, 0};
  bf16x8 b8 = {b[0], b[1], b[2], b[3], 0, 0, 0, 0};
  return mfma16(a8, b8, c);
}
#endif
// Async global->LDS, 16B per lane. LDS dest = wave-uniform base + lane*16.
static __device__ __forceinline__ void glds16(const void* g, void* l) {
  __builtin_amdgcn_global_load_lds((const __attribute__((address_space(1))) u32*)g,
                                   (__attribute__((address_space(3))) u32*)l, 16, 0, 0);
}

__global__ __launch_bounds__(256) void cast_bf16(const float* __restrict__ src,
                                                 u16* __restrict__ dst, int n4) {
  int i = blockIdx.x * 256 + threadIdx.x;
  if (i >= n4) return;
  const float* s = src + (size_t)i * 4;
  u16x4 o;
  o.x = f2bf(s[0]); o.y = f2bf(s[1]); o.z = f2bf(s[2]); o.w = f2bf(s[3]);
  ((u16x4*)dst)[i] = o;
}

// All four weight matrices -> one contiguous bf16 block [4096][1024].
__global__ __launch_bounds__(256) void cast_w4(const float* __restrict__ a,
                                               const float* __restrict__ b,
                                               const float* __restrict__ c2,
                                               const float* __restrict__ d,
                                               u16* __restrict__ dst) {
  const int per = DMODEL * DMODEL / 4;  // 2^18 quads per matrix
  int i = blockIdx.x * 256 + threadIdx.x;
  if (i >= 4 * per) return;
  int sel = i >> 18;
  const float* s = (sel == 0) ? a : (sel == 1) ? b : (sel == 2) ? c2 : d;
  s += (size_t)(i & (per - 1)) * 4;
  u16x4 o;
  o.x = f2bf(s[0]); o.y = f2bf(s[1]); o.z = f2bf(s[2]); o.w = f2bf(s[3]);
  ((u16x4*)dst)[i] = o;
}

// C[m,n] = sum_k A[m,k] * W[n,k]. 128x128 tile, BK=64, glds staging.
// mode 0: QKV epilogue (n<1024 -> oq, <2048 -> ok, else ov as [B,H,DK,S]).
// mode 2: fp32 store to of.
__global__ __launch_bounds__(256) void gemm128(const u16* __restrict__ A,
                                               const u16* __restrict__ W,
                                               u16* __restrict__ oq,
                                               u16* __restrict__ ok,
                                               u16* __restrict__ ov,
                                               float* __restrict__ of,
                                               int mode) {
  __shared__ __attribute__((aligned(16))) u16 As[128 * 64];
  __shared__ __attribute__((aligned(16))) u16 Bs[128 * 64];
  const int m0 = blockIdx.x * 128, n0 = blockIdx.y * 128;
  const int tid = threadIdx.x, lane = tid & 63, wave = tid >> 6;
  const int quad = lane >> 4, c = lane & 15;
  const int wm = (wave & 1) * 64, wn = (wave >> 1) * 64;
  const int ls = lane >> 3, lc = lane & 7;
  f32x4 acc[4][4] = {};
  for (int ko = 0; ko < DMODEL; ko += 64) {
#pragma unroll
    for (int i = 0; i < 4; ++i) {
      int rb = i * 32 + wave * 8;
      int r = rb + ls;
      int kA = ko + 8 * (lc ^ (r & 7));
      glds16(&A[(size_t)(m0 + r) * DMODEL + kA], &As[rb * 64]);
      glds16(&W[(size_t)(n0 + r) * DMODEL + kA], &Bs[rb * 64]);
    }
    __syncthreads();
#pragma unroll
    for (int t = 0; t < 2; ++t) {
      bf16x8 af[4], bfr[4];
#pragma unroll
      for (int mb = 0; mb < 4; ++mb) {
        int r = wm + mb * 16 + c;
        af[mb] = *(const bf16x8*)&As[r * 64 + 8 * ((t * 4 + quad) ^ (r & 7))];
      }
#pragma unroll
      for (int nb = 0; nb < 4; ++nb) {
        int r = wn + nb * 16 + c;
        bfr[nb] = *(const bf16x8*)&Bs[r * 64 + 8 * ((t * 4 + quad) ^ (r & 7))];
      }
#pragma unroll
      for (int mb = 0; mb < 4; ++mb)
#pragma unroll
        for (int nb = 0; nb < 4; ++nb)
          acc[mb][nb] = mfma16(af[mb], bfr[nb], acc[mb][nb]);
    }
    __syncthreads();
  }
#pragma unroll
  for (int mb = 0; mb < 4; ++mb) {
    int mrow = m0 + wm + mb * 16 + quad * 4;
#pragma unroll
    for (int nb = 0; nb < 4; ++nb) {
      int n = n0 + wn + nb * 16 + c;
      f32x4 v = acc[mb][nb];
      if (mode == 2) {
#pragma unroll
        for (int r = 0; r < 4; ++r) of[(size_t)(mrow + r) * DMODEL + n] = v[r];
      } else if (n < DMODEL) {
#pragma unroll
        for (int r = 0; r < 4; ++r) oq[(size_t)(mrow + r) * DMODEL + n] = f2bf(v[r]);
      } else if (n < 2 * DMODEL) {
#pragma unroll
        for (int r = 0; r < 4; ++r) ok[(size_t)(mrow + r) * DMODEL + (n - DMODEL)] = f2bf(v[r]);
      } else {
        int nn = n - 2 * DMODEL;
        int h = nn >> 6, d = nn & 63;
        int b = mrow >> 11, s = mrow & (S_LEN - 1);
        u16x4 p4;
        p4.x = f2bf(v[0]); p4.y = f2bf(v[1]); p4.z = f2bf(v[2]); p4.w = f2bf(v[3]);
        *(u16x4*)&ov[((size_t)(b * NHEAD + h) * DKH + d) * S_LEN + s] = p4;
      }
    }
  }
}

// In-place RoPE on q and k; q additionally pre-scaled by 0.125*log2(e) so
// attention scores exit QK^T MFMA directly in the log2 domain.
__global__ __launch_bounds__(256) void rope_qk(u16* __restrict__ q, u16* __restrict__ k,
                                               const int* __restrict__ pos) {
  const float QSCALE = 0.18033688011112042f;  // 0.125 * log2(e)
  int i = blockIdx.x * 256 + threadIdx.x;  // pair index over [8192][512]
  if (i >= BATCH * S_LEN * DMODEL / 2) return;
  int m = i >> 9;
  int pr = i & 511;
  int p = pr & 31;
  int s = m & (S_LEN - 1);
  float ph = (float)pos[s] * powf(10000.0f, -(float)(2 * p) / 64.0f);
  float sn, cs;
  sincosf(ph, &sn, &cs);
  unsigned vq = ((unsigned*)q)[i];
  float x1, x2, r1, r2;
  { union { u32 u; float f; } a, b2; a.u = vq << 16; b2.u = vq & 0xffff0000u;
    x1 = a.f; x2 = b2.f; }
  r1 = (x1 * cs - x2 * sn) * QSCALE; r2 = (x1 * sn + x2 * cs) * QSCALE;
  ((unsigned*)q)[i] = pack2bf(r1, r2);
  unsigned vk = ((unsigned*)k)[i];
  { union { u32 u; float f; } a, b2; a.u = vk << 16; b2.u = vk & 0xffff0000u;
    x1 = a.f; x2 = b2.f; }
  r1 = x1 * cs - x2 * sn; r2 = x1 * sn + x2 * cs;
  ((unsigned*)k)[i] = pack2bf(r1, r2);
}

// Flash attention, S^T formulation, no-max softmax, LDS-FREE.
// Block = 4 waves; wave w handles (bh = blockIdx.y, qt from balanced set
// {x, 31-x, 15-x, 16+x}) so every block does exactly 66 tile-applications.
// Each wave owns 64 q-rows (4 x 16-col MFMA groups); K fragments (b128) and
// V fragments (b64, K=16 A-operand layout from vt=[B,H,DK,S]) are loaded
// directly from global — no LDS, no barriers. Grid (8, 64) = 512 blocks.
__global__ __launch_bounds__(256) void attn5(const u16* __restrict__ qb,
                                             const u16* __restrict__ kb,
                                             const u16* __restrict__ vt,
                                             u16* __restrict__ ab) {
  const int tid = threadIdx.x, lane = tid & 63, w = tid >> 6;
  const int bh = blockIdx.y, b = bh >> 4, h = bh & 15;
  const int x = blockIdx.x;  // 0..7
  const int qt = (w == 0) ? x : (w == 1) ? (NT - 1 - x) : (w == 2) ? (15 - x) : (16 + x);
  const int quad = lane >> 4, c = lane & 15;
  const int q0 = qt * 64;
  const float NEG = -3.0e38f;

  bf16x8 qf[4][2];
#pragma unroll
  for (int g = 0; g < 4; ++g) {
    const u16* qp = qb + (size_t)(b * S_LEN + q0 + g * 16 + c) * DMODEL + h * DKH;
    qf[g][0] = *(const bf16x8*)&qp[quad * 8];
    qf[g][1] = *(const bf16x8*)&qp[32 + quad * 8];
  }
  float li[4] = {0.f, 0.f, 0.f, 0.f};
  f32x4 od[4][4] = {};  // [q-group][d-block]

  const u16* kbase = kb + (size_t)b * S_LEN * DMODEL + h * DKH;
  const u16* vbase = vt + (size_t)bh * DKH * S_LEN;

#pragma unroll 1
  for (int j = 0; j <= qt; ++j) {
    // K fragments straight from global: B-operand, keys kbi*16+c, k=quad*8+t
    bf16x8 kf[4][2];
#pragma unroll
    for (int kbi = 0; kbi < 4; ++kbi) {
      const u16* kp = kbase + (size_t)(j * 64 + kbi * 16 + c) * DMODEL;
      kf[kbi][0] = *(const bf16x8*)&kp[quad * 8];
      kf[kbi][1] = *(const bf16x8*)&kp[32 + quad * 8];
    }
    // V fragments straight from global: K=16 A-operand, m=d (c), k=quad*4+r
    bf16x4 vf[4][4];  // [d-block][key-block]
#pragma unroll
    for (int db = 0; db < 4; ++db) {
      const u16* vp = vbase + (size_t)(db * 16 + c) * S_LEN + j * 64 + quad * 4;
#pragma unroll
      for (int kbi = 0; kbi < 4; ++kbi)
        vf[db][kbi] = *(const bf16x4*)&vp[kbi * 16];
    }
    const bool diag = (j == qt);
#pragma unroll
    for (int g = 0; g < 4; ++g) {
      f32x4 sc[4];
#pragma unroll
      for (int kbi = 0; kbi < 4; ++kbi) {
        f32x4 a = {};
        a = mfma16(kf[kbi][0], qf[g][0], a);
        a = mfma16(kf[kbi][1], qf[g][1], a);
        sc[kbi] = a;  // log2-domain scores (q pre-scaled)
      }
      if (diag) {
#pragma unroll
        for (int kbi = 0; kbi < 4; ++kbi)
#pragma unroll
          for (int r = 0; r < 4; ++r)
            if (kbi * 16 + quad * 4 + r > g * 16 + c) sc[kbi][r] = NEG;
      }
      float rs = 0.f;
#pragma unroll
      for (int kbi = 0; kbi < 4; ++kbi)
#pragma unroll
        for (int r = 0; r < 4; ++r) {
          float pv = fexp2(sc[kbi][r]);
          sc[kbi][r] = pv;
          rs += pv;
        }
      rs += __shfl_xor(rs, 16);
      rs += __shfl_xor(rs, 32);
      li[g] += rs;
      bf16x4 pkv[4];
#pragma unroll
      for (int kbi = 0; kbi < 4; ++kbi) {
        union { u32 ww[2]; bf16x4 v; } pk;
        pk.ww[0] = pack2bf(sc[kbi][0], sc[kbi][1]);
        pk.ww[1] = pack2bf(sc[kbi][2], sc[kbi][3]);
        pkv[kbi] = pk.v;
      }
#pragma unroll
      for (int db = 0; db < 4; ++db)
#pragma unroll
        for (int kbi = 0; kbi < 4; ++kbi)
          od[g][db] = mfma16k16(vf[db][kbi], pkv[kbi], od[g][db]);
    }
  }

#pragma unroll
  for (int g = 0; g < 4; ++g) {
    float inv = 1.0f / li[g];
    u16* op = ab + (size_t)(b * S_LEN + q0 + g * 16 + c) * DMODEL + h * DKH;
#pragma unroll
    for (int db = 0; db < 4; ++db) {
      u16x4 o4;
      o4.x = f2bf(od[g][db][0] * inv);
      o4.y = f2bf(od[g][db][1] * inv);
      o4.z = f2bf(od[g][db][2] * inv);
      o4.w = f2bf(od[g][db][3] * inv);
      *(u16x4*)&op[db * 16 + quad * 4] = o4;
    }
  }
}

extern "C" void kernel_launch(void* const* d_in, const int* in_sizes, int n_in,
                              void* d_out, int out_size, void* d_ws, size_t ws_size,
                              hipStream_t stream) {
  const float* x = (const float*)d_in[0];
  const int* pos = (const int*)d_in[1];
  const float* Wq = (const float*)d_in[2];
  const float* Wk = (const float*)d_in[3];
  const float* Wv = (const float*)d_in[4];
  const float* Wo = (const float*)d_in[5];
  float* out = (float*)d_out;

  char* w = (char*)d_ws;
  size_t o = 0;
  auto take = [&](size_t nbytes) {
    char* p = w + o;
    o += (nbytes + 255) & ~(size_t)255;
    return p;
  };
  const size_t actBytes = (size_t)BATCH * S_LEN * DMODEL * 2;
  const size_t wElems = (size_t)DMODEL * DMODEL;
  u16* xb   = (u16*)take(actBytes);
  u16* Wall = (u16*)take(4 * wElems * 2);  // Wq;Wk;Wv;Wo bf16
  u16* qb   = (u16*)take(actBytes);
  u16* kb   = (u16*)take(actBytes);
  u16* vt   = (u16*)take(actBytes);  // [B,H,DK,S]
  u16* ab   = (u16*)take(actBytes);

  int n4x = BATCH * S_LEN * DMODEL / 4;
  cast_bf16<<<(n4x + 255) / 256, 256, 0, stream>>>(x, xb, n4x);
  int n4w = 4 * DMODEL * DMODEL / 4;
  cast_w4<<<(n4w + 255) / 256, 256, 0, stream>>>(Wq, Wk, Wv, Wo, Wall);

  // Fused QKV: [8192,1024] x [3072,1024]^T
  gemm128<<<dim3(BATCH * S_LEN / 128, 3 * DMODEL / 128), 256, 0, stream>>>(
      xb, Wall, qb, kb, vt, nullptr, 0);

  int npair = BATCH * S_LEN * DMODEL / 2;
  rope_qk<<<(npair + 255) / 256, 256, 0, stream>>>(qb, kb, pos);

  attn5<<<dim3(8, BATCH * NHEAD), 256, 0, stream>>>(qb, kb, vt, ab);

  gemm128<<<dim3(BATCH * S_LEN / 128, DMODEL / 128), 256, 0, stream>>>(
      ab, Wall + 3 * wElems, nullptr, nullptr, nullptr, out, 2);
}